// Round 4
// baseline (10557.233 us; speedup 1.0000x reference)
//
#include <hip/hip_runtime.h>
#include <hip/hip_bf16.h>

#define NNODES 100000
#define NRELS  16
#define NEDGES 1600000
#define NBLKS  782               // ceil(NNODES/128)
#define NKEYS  (NBLKS * 16)      // 12512

// ---------------- ws layout (bytes) ----------------
// invcnt  : N*16 f32      @ 0           (6,400,000)
// offs    : NKEYS+1 int   @ 6,400,000   (50,052)
// cur     : NKEYS int     @ 6,450,064   (50,048)
// eSrcRow : E int         @ 6,500,112   (6,400,000)   src | (tgt&127)<<20
// eScale  : E f32         @ 12,900,112  (6,400,000)
// W       : 16*128*128 f32@ 19,300,112  (1,048,576)
// total   : 20,348,688

// per-(tgt,rel) counts + per-(tgtblock,rel) histogram
__global__ void hist_kernel(const int* __restrict__ tgt, const int* __restrict__ et,
                            float* __restrict__ cnt, int* __restrict__ keyCnt) {
    int e = blockIdx.x * 256 + threadIdx.x;
    if (e >= NEDGES) return;
    int t = tgt[e], r = et[e];
    atomicAdd(&cnt[t * 16 + r], 1.0f);
    atomicAdd(&keyCnt[(t >> 7) * 16 + r], 1);
}

// exclusive scan of cur[NKEYS] -> offs; also cur <- offs (scatter cursors)
__global__ void scan_kernel(int* __restrict__ cur, int* __restrict__ offs) {
    __shared__ int part[256];
    int t = threadIdx.x;
    int lo = t * 49, hi = min(lo + 49, NKEYS);
    int s = 0;
    for (int i = lo; i < hi; ++i) s += cur[i];
    part[t] = s;
    __syncthreads();
    if (t == 0) {
        int run = 0;
        for (int i = 0; i < 256; ++i) { int v = part[i]; part[i] = run; run += v; }
        offs[NKEYS] = run;
    }
    __syncthreads();
    int run = part[t];
    for (int i = lo; i < hi; ++i) {
        int c = cur[i];
        offs[i] = run; cur[i] = run; run += c;
    }
}

__global__ void invcnt_kernel(float* __restrict__ cnt) {
    int i = blockIdx.x * 256 + threadIdx.x;
    if (i < NNODES * 16) cnt[i] = 1.0f / fmaxf(cnt[i], 1.0f);
}

// counting-sort scatter into packed edge records
__global__ void scatter_edges(const int* __restrict__ src, const int* __restrict__ tgt,
                              const int* __restrict__ et, const float* __restrict__ invcnt,
                              int* __restrict__ cur,
                              int* __restrict__ eSrcRow, float* __restrict__ eScale) {
    int e = blockIdx.x * 256 + threadIdx.x;
    if (e >= NEDGES) return;
    int t = tgt[e], r = et[e];
    int key = (t >> 7) * 16 + r;
    int pos = atomicAdd(&cur[key], 1);
    eSrcRow[pos] = src[e] | ((t & 127) << 20);
    eScale[pos] = invcnt[t * 16 + r];
}

// W[r] = sum_b comp[r][b] * basis[b]   (16 x 128 x 128)
__global__ void wcomp_kernel(const float* __restrict__ comp, const float* __restrict__ basis,
                             float* __restrict__ W) {
    int q = blockIdx.x * 256 + threadIdx.x;   // float4 index, 65536 total
    int idx = q * 4;
    int r = idx >> 14, io = idx & 16383;
    float ax = 0.f, ay = 0.f, az = 0.f, aw = 0.f;
    #pragma unroll
    for (int b = 0; b < 12; ++b) {
        float c = comp[r * 12 + b];
        const float4 v = *reinterpret_cast<const float4*>(basis + b * 16384 + io);
        ax += c * v.x; ay += c * v.y; az += c * v.z; aw += c * v.w;
    }
    float4 o; o.x = ax; o.y = ay; o.z = az; o.w = aw;
    *reinterpret_cast<float4*>(W + idx) = o;
}

// Fused per-layer kernel. Block b owns target nodes [b*128, b*128+128).
// Per relation: stage W[rel] (64KB) in LDS ONCE; then 64-edge x 128-col tiles,
// A double-buffered (global->reg overlapped with compute, reg->LDS, 1 barrier
// per 32-k chunk). Thread-tile: 8 rows (ry+8i) x 4 cols (cx*4..+3). Scaled
// LDS-atomic accumulate into acc[128][132]; bias init, fused ReLU store.
__global__ __launch_bounds__(256) void layer_kernel(
    const float* __restrict__ x, int xs,
    const float* __restrict__ W, const float* __restrict__ root,
    const float* __restrict__ bias,
    const int* __restrict__ eSrcRow, const float* __restrict__ eScale,
    const int* __restrict__ offs,
    float* __restrict__ out, int colOff)
{
    const int b = blockIdx.x;
    const int node0 = b * 128;
    const int nIn = min(128, NNODES - node0);
    __shared__ float acc[128 * 132];   // 67,584 B
    __shared__ float Wl[128 * 128];    // 65,536 B
    __shared__ float As[2][64 * 36];   // 18,432 B
    __shared__ int   sMeta[64];
    __shared__ float sScale[64];       // total 152,064 B <= 160 KiB
    const int tid = threadIdx.x;
    const int cx = tid & 31;           // col group: cols cx*4 .. cx*4+3
    const int ry = tid >> 5;           // row base: rows ry + 8*i, i = 0..7
    const int arr = tid >> 2;          // A-gather row
    const int ac0 = (tid & 3) * 8;     // A-gather col offset

    // init acc with bias
    for (int i = tid; i < 128 * 128; i += 256)
        acc[(i >> 7) * 132 + (i & 127)] = bias[i & 127];

    for (int rel = 0; rel < 17; ++rel) {
        __syncthreads();   // prior readers of Wl / As / sMeta are done
        // stage W for this relation (16 float4 per thread, coalesced)
        const float* Wr = (rel < 16) ? (W + rel * 16384) : root;
        #pragma unroll
        for (int q = 0; q < 16; ++q) {
            int f4 = tid + 256 * q;
            *reinterpret_cast<float4*>(&Wl[f4 * 4]) =
                *reinterpret_cast<const float4*>(Wr + f4 * 4);
        }
        int s0, s1;
        if (rel < 16) { s0 = offs[b * 16 + rel]; s1 = offs[b * 16 + rel + 1]; }
        else          { s0 = 0; s1 = nIn; }

        for (int t0 = s0; t0 < s1; t0 += 64) {
            if (tid < 64) {   // tile meta
                int ei = t0 + tid;
                if (ei < s1) {
                    if (rel < 16) { sMeta[tid] = eSrcRow[ei]; sScale[tid] = eScale[ei]; }
                    else { sMeta[tid] = (node0 + ei) | (ei << 20); sScale[tid] = 1.0f; }
                } else { sMeta[tid] = 0; sScale[tid] = 0.0f; }   // pad: scale 0
            }
            __syncthreads();   // meta ready; Wl ready (first tile)

            // hoist this thread's 8 rows' scatter meta
            int m[8]; float sc[8];
            #pragma unroll
            for (int i = 0; i < 8; ++i) { m[i] = sMeta[ry + 8 * i]; sc[i] = sScale[ry + 8 * i]; }

            // prologue: gather A chunk kc=0 into As[0]
            {
                const float* s = x + (size_t)(sMeta[arr] & 0xFFFFF) * xs + ac0;
                float4 v0 = *reinterpret_cast<const float4*>(s);
                float4 v1 = *reinterpret_cast<const float4*>(s + 4);
                *reinterpret_cast<float4*>(&As[0][arr * 36 + ac0]) = v0;
                *reinterpret_cast<float4*>(&As[0][arr * 36 + ac0 + 4]) = v1;
            }
            __syncthreads();

            float racc[8][4] = {};
            for (int kc = 0; kc < 4; ++kc) {
                float4 p0, p1;
                if (kc < 3) {   // issue next A chunk (latency hides under compute)
                    const float* s = x + (size_t)(sMeta[arr] & 0xFFFFF) * xs + (kc + 1) * 32 + ac0;
                    p0 = *reinterpret_cast<const float4*>(s);
                    p1 = *reinterpret_cast<const float4*>(s + 4);
                }
                const float* Ab = As[kc & 1];
                #pragma unroll
                for (int kk = 0; kk < 32; kk += 4) {
                    float4 av[8];
                    #pragma unroll
                    for (int i = 0; i < 8; ++i)
                        av[i] = *reinterpret_cast<const float4*>(&Ab[(ry + 8 * i) * 36 + kk]);
                    #pragma unroll
                    for (int j = 0; j < 4; ++j) {
                        const float4 wv = *reinterpret_cast<const float4*>(
                            &Wl[(kc * 32 + kk + j) * 128 + cx * 4]);
                        #pragma unroll
                        for (int i = 0; i < 8; ++i) {
                            const float a = (j == 0) ? av[i].x : (j == 1) ? av[i].y
                                          : (j == 2) ? av[i].z : av[i].w;
                            racc[i][0] += a * wv.x; racc[i][1] += a * wv.y;
                            racc[i][2] += a * wv.z; racc[i][3] += a * wv.w;
                        }
                    }
                }
                if (kc < 3) {
                    float* d = &As[(kc + 1) & 1][arr * 36 + ac0];
                    *reinterpret_cast<float4*>(d)     = p0;
                    *reinterpret_cast<float4*>(d + 4) = p1;
                    __syncthreads();
                }
            }
            // scaled LDS-atomic scatter into acc (j rotated to spread banks)
            #pragma unroll
            for (int i = 0; i < 8; ++i) {
                float* p = &acc[(m[i] >> 20) * 132 + cx * 4];
                const float s = sc[i];
                #pragma unroll
                for (int j = 0; j < 4; ++j) {
                    int jj = (j + ry) & 3;
                    atomicAdd(p + jj, racc[i][jj] * s);
                }
            }
        }
    }
    __syncthreads();
    // fused ReLU + store into concat slot
    for (int q = tid; q < nIn * 32; q += 256) {
        int r = q >> 5, c = (q & 31) * 4;
        float4 v = *reinterpret_cast<const float4*>(&acc[r * 132 + c]);
        v.x = fmaxf(v.x, 0.f); v.y = fmaxf(v.y, 0.f);
        v.z = fmaxf(v.z, 0.f); v.w = fmaxf(v.w, 0.f);
        *reinterpret_cast<float4*>(out + (size_t)(node0 + r) * 512 + colOff + c) = v;
    }
}

__global__ void emb_copy(const float* __restrict__ emb, float* __restrict__ out) {
    int q = blockIdx.x * 256 + threadIdx.x;
    int n = q >> 5, c = (q & 31) * 4;
    float4 v = *reinterpret_cast<const float4*>(emb + (size_t)n * 128 + c);
    *reinterpret_cast<float4*>(out + (size_t)n * 512 + 384 + c) = v;
}

extern "C" void kernel_launch(void* const* d_in, const int* in_sizes, int n_in,
                              void* d_out, int out_size, void* d_ws, size_t ws_size,
                              hipStream_t stream) {
    const float* emb = (const float*)d_in[0];
    const float* comp[3]  = {(const float*)d_in[1], (const float*)d_in[5], (const float*)d_in[9]};
    const float* basis[3] = {(const float*)d_in[2], (const float*)d_in[6], (const float*)d_in[10]};
    const float* root[3]  = {(const float*)d_in[3], (const float*)d_in[7], (const float*)d_in[11]};
    const float* bias[3]  = {(const float*)d_in[4], (const float*)d_in[8], (const float*)d_in[12]};
    const int* src = (const int*)d_in[13];
    const int* tgt = (const int*)d_in[14];
    const int* et  = (const int*)d_in[15];
    float* out = (float*)d_out;

    char* ws = (char*)d_ws;
    float* invcnt  = (float*)ws;                  // N*16 f32
    int*   offs    = (int*)(ws + 6400000);        // NKEYS+1
    int*   cur     = (int*)(ws + 6450064);        // NKEYS
    int*   eSrcRow = (int*)(ws + 6500112);        // E
    float* eScale  = (float*)(ws + 12900112);     // E
    float* W       = (float*)(ws + 19300112);     // 16*128*128
    if (ws_size < 20348688) return;

    hipMemsetAsync(invcnt, 0, 6400000, stream);
    hipMemsetAsync(cur, 0, NKEYS * 4, stream);
    hist_kernel<<<6250, 256, 0, stream>>>(tgt, et, invcnt, cur);
    scan_kernel<<<1, 256, 0, stream>>>(cur, offs);
    invcnt_kernel<<<6250, 256, 0, stream>>>(invcnt);
    scatter_edges<<<6250, 256, 0, stream>>>(src, tgt, et, invcnt, cur, eSrcRow, eScale);

    const float* xin[3] = {emb, out + 256, out + 128};
    const int    xs[3]  = {128, 512, 512};
    const int    colOff[3] = {256, 128, 0};

    for (int l = 0; l < 3; ++l) {
        wcomp_kernel<<<256, 256, 0, stream>>>(comp[l], basis[l], W);
        layer_kernel<<<NBLKS, 256, 0, stream>>>(xin[l], xs[l], W, root[l], bias[l],
                                                eSrcRow, eScale, offs, out, colOff[l]);
    }
    emb_copy<<<12500, 256, 0, stream>>>(emb, out);
}

// Round 8
// 4879.221 us; speedup vs baseline: 2.1637x; 2.1637x over previous
//
#include <hip/hip_runtime.h>
#include <hip/hip_bf16.h>

#define NNODES 100000
#define NRELS  16
#define NEDGES 1600000
#define NBLKS  782               // ceil(NNODES/128)
#define NKEYS  (NBLKS * 16)      // 12512
#define GRID_MFMA 512            // persistent blocks (2/CU), job-counter balanced

typedef unsigned short u16;
typedef unsigned int   u32;
typedef __attribute__((ext_vector_type(8))) short short8;   // 8 bf16 (4 VGPRs)
typedef __attribute__((ext_vector_type(4))) float f32x4;

// ---------------- ws layout (bytes) ----------------
#define WS_INVCNT   0            // N*16 f32                6,400,000
#define WS_OFFS     6400000      // NKEYS+1 int
#define WS_CUR      6450064      // NKEYS int
#define WS_EMETA    6500112      // E int2 {src|(tgt&127)<<20, scale_bits}
#define WS_WTHI     19300112     // 17*128*128 bf16  [rel][col][k]
#define WS_WTLO     19857168
#define WS_CTR      20414224     // 4 job counters
#define WS_END      20414240     // ~20.4 MB (R4 proved ws >= 65 MB)

#define MFMA16(a, b, c) __builtin_amdgcn_mfma_f32_16x16x32_bf16((a), (b), (c), 0, 0, 0)

__device__ __forceinline__ u16 bf16_rne(float v) {
    u32 u = __float_as_uint(v);
    u32 r = (u + 0x7FFFu + ((u >> 16) & 1u)) >> 16;
    return (u16)r;
}

// ---------------- preprocessing ----------------
__global__ void hist_kernel(const int* __restrict__ tgt, const int* __restrict__ et,
                            float* __restrict__ cnt, int* __restrict__ keyCnt) {
    int e = blockIdx.x * 256 + threadIdx.x;
    if (e >= NEDGES) return;
    int t = tgt[e], r = et[e];
    atomicAdd(&cnt[t * 16 + r], 1.0f);
    atomicAdd(&keyCnt[(t >> 7) * 16 + r], 1);
}

__global__ void scan_kernel(int* __restrict__ cur, int* __restrict__ offs) {
    __shared__ int part[256];
    int t = threadIdx.x;
    int lo = t * 49, hi = min(lo + 49, NKEYS);
    int s = 0;
    for (int i = lo; i < hi; ++i) s += cur[i];
    part[t] = s;
    __syncthreads();
    if (t == 0) {
        int run = 0;
        for (int i = 0; i < 256; ++i) { int v = part[i]; part[i] = run; run += v; }
        offs[NKEYS] = run;
    }
    __syncthreads();
    int run = part[t];
    for (int i = lo; i < hi; ++i) {
        int c = cur[i];
        offs[i] = run; cur[i] = run; run += c;
    }
}

__global__ void invcnt_kernel(float* __restrict__ cnt) {
    int i = blockIdx.x * 256 + threadIdx.x;
    if (i < NNODES * 16) cnt[i] = 1.0f / fmaxf(cnt[i], 1.0f);
}

__global__ void scatter_edges(const int* __restrict__ src, const int* __restrict__ tgt,
                              const int* __restrict__ et, const float* __restrict__ invcnt,
                              int* __restrict__ cur, int2* __restrict__ eMeta) {
    int e = blockIdx.x * 256 + threadIdx.x;
    if (e >= NEDGES) return;
    int t = tgt[e], r = et[e];
    int key = (t >> 7) * 16 + r;
    int pos = atomicAdd(&cur[key], 1);
    int2 m;
    m.x = src[e] | ((t & 127) << 20);
    m.y = __float_as_int(invcnt[t * 16 + r]);
    eMeta[pos] = m;
}

// Wt[rel][col][k]: rel<16 = sum_b comp[r][b]*basis[b][k][col]; rel 16 = root[k][col]
__global__ void wprep_kernel(const float* __restrict__ comp, const float* __restrict__ basis,
                             const float* __restrict__ root,
                             u16* __restrict__ Wthi, u16* __restrict__ Wtlo) {
    int t = blockIdx.x * 256 + threadIdx.x;   // 17*128*32 = 69632
    if (t >= 17 * 128 * 32) return;
    int k4 = (t & 31) * 4, col = (t >> 5) & 127, rel = t >> 12;
    float v[4];
    if (rel < 16) {
        v[0] = v[1] = v[2] = v[3] = 0.f;
        #pragma unroll
        for (int b = 0; b < 12; ++b) {
            float c = comp[rel * 12 + b];
            #pragma unroll
            for (int kk = 0; kk < 4; ++kk)
                v[kk] += c * basis[b * 16384 + (k4 + kk) * 128 + col];
        }
    } else {
        #pragma unroll
        for (int kk = 0; kk < 4; ++kk) v[kk] = root[(k4 + kk) * 128 + col];
    }
    ushort4 h, l;
    u16* hp = (u16*)&h; u16* lp = (u16*)&l;
    #pragma unroll
    for (int kk = 0; kk < 4; ++kk) {
        hp[kk] = bf16_rne(v[kk]);
        lp[kk] = bf16_rne(v[kk] - __uint_as_float((u32)hp[kk] << 16));
    }
    size_t o = (size_t)rel * 16384 + col * 128 + k4;
    *reinterpret_cast<ushort4*>(Wthi + o) = h;
    *reinterpret_cast<ushort4*>(Wtlo + o) = l;
}

// ---------------- MFMA fused layer ----------------
// Persistent blocks grab 128-target jobs via a global counter. 4 waves; wave w
// owns output cols w*32..+31; B = W^T hi/lo in 64 VGPRs per relation (incl.
// virtual self-loop rel 16). x is read as PLAIN F32 (emb for L1, the already-
// written out-slots for L2/L3) and split to hi/lo bf16 in registers at use.
// 16-edge tiles, register-double-buffered (next tile's loads issue before this
// tile's MFMAs). 3-term split-bf16 MFMA 16x16x32 (rel err ~2^-16). Scaled
// LDS-atomic scatter into accS[128][132]; bias init; fused ReLU f32 store.
__global__ __launch_bounds__(256, 2) void layer_mfma(
    const float* __restrict__ xp, int xstride,
    const u16* __restrict__ Wthi, const u16* __restrict__ Wtlo,
    const float* __restrict__ bias,
    const int2* __restrict__ eMeta, const int* __restrict__ offs,
    int* __restrict__ jobCtr,
    float* __restrict__ out, int colOff)
{
    __shared__ float accS[128 * 132];   // 67,584 B -> 2 blocks/CU
    __shared__ int sJb;
    const int tid = threadIdx.x;
    const int w  = tid >> 6;            // wave = col group 0..3
    const int l  = tid & 63;
    const int g  = l >> 4;              // k-octet / D-row group
    const int ln = l & 15;              // A row in tile / D col
    const int colb = w * 32;

    short8 Bh[2][4], Bl[2][4];          // [nfrag][kc] : 64 VGPR

    while (true) {
        if (tid == 0) sJb = atomicAdd(jobCtr, 1);
        __syncthreads();
        const int b = sJb;
        if (b >= NBLKS) break;
        const int node0 = b * 128;
        const int nIn = min(128, NNODES - node0);

        for (int i = tid; i < 128 * 128; i += 256)
            accS[(i >> 7) * 132 + (i & 127)] = bias[i & 127];
        __syncthreads();

        for (int rel = 0; rel <= 16; ++rel) {
            int s0, s1;
            if (rel < 16) { s0 = offs[b * 16 + rel]; s1 = offs[b * 16 + rel + 1]; }
            else          { s0 = 0; s1 = nIn; }
            if (s0 >= s1) continue;

            {   // B fragments for this relation (Wt is [rel][col][k])
                const u16* ph = Wthi + (size_t)rel * 16384 + (colb + ln) * 128 + g * 8;
                const u16* pl = Wtlo + (size_t)rel * 16384 + (colb + ln) * 128 + g * 8;
                #pragma unroll
                for (int nf = 0; nf < 2; ++nf)
                    #pragma unroll
                    for (int kc = 0; kc < 4; ++kc) {
                        Bh[nf][kc] = *(const short8*)(ph + nf * 2048 + kc * 32);
                        Bl[nf][kc] = *(const short8*)(pl + nf * 2048 + kc * 32);
                    }
            }

            // load tile t0: raw f32 A row-segment (8 float4) + scatter meta
            auto loadT = [&](int t0, float4* raw, int* tg, float* sc) {
                int aSrc;
                if (rel < 16) {
                    aSrc = eMeta[min(t0 + ln, s1 - 1)].x & 0xFFFFF;
                    #pragma unroll
                    for (int j = 0; j < 4; ++j) {
                        int ei = t0 + 4 * g + j;
                        int2 mj = eMeta[min(ei, s1 - 1)];
                        tg[j] = (mj.x >> 20) & 127;
                        sc[j] = (ei < s1) ? __int_as_float(mj.y) : 0.f;
                    }
                } else {   // virtual self-loop relation
                    aSrc = node0 + min(t0 + ln, s1 - 1);
                    #pragma unroll
                    for (int j = 0; j < 4; ++j) {
                        int ei = t0 + 4 * g + j;
                        tg[j] = min(ei, s1 - 1);
                        sc[j] = (ei < s1) ? 1.f : 0.f;
                    }
                }
                const float* pa = xp + (size_t)aSrc * xstride + g * 8;
                #pragma unroll
                for (int kc = 0; kc < 4; ++kc) {
                    raw[2 * kc]     = *reinterpret_cast<const float4*>(pa + kc * 32);
                    raw[2 * kc + 1] = *reinterpret_cast<const float4*>(pa + kc * 32 + 4);
                }
            };
            // in-register f32->hi/lo split + 3-term MFMA + scaled LDS scatter
            auto computeT = [&](const float4* raw, const int* tg, const float* sc) {
                f32x4 a0 = {0.f, 0.f, 0.f, 0.f}, a1 = {0.f, 0.f, 0.f, 0.f};
                #pragma unroll
                for (int kc = 0; kc < 4; ++kc) {
                    short8 ah, al;
                    const float* f = reinterpret_cast<const float*>(&raw[2 * kc]);
                    #pragma unroll
                    for (int j = 0; j < 8; ++j) {
                        u32 u = __float_as_uint(f[j]);
                        u16 h = (u16)(u >> 16);                       // trunc hi
                        float d = f[j] - __uint_as_float((u32)h << 16);
                        ah[j] = (short)h;
                        al[j] = (short)bf16_rne(d);                   // exact-ish lo
                    }
                    a0 = MFMA16(al, Bh[0][kc], a0);
                    a0 = MFMA16(ah, Bl[0][kc], a0);
                    a0 = MFMA16(ah, Bh[0][kc], a0);
                    a1 = MFMA16(al, Bh[1][kc], a1);
                    a1 = MFMA16(ah, Bl[1][kc], a1);
                    a1 = MFMA16(ah, Bh[1][kc], a1);
                }
                #pragma unroll
                for (int j = 0; j < 4; ++j) {   // D: row=(lane>>4)*4+j, col=lane&15
                    if (sc[j] != 0.f) {
                        float* p = &accS[tg[j] * 132 + colb + ln];
                        atomicAdd(p,      a0[j] * sc[j]);
                        atomicAdd(p + 16, a1[j] * sc[j]);
                    }
                }
            };

            float4 rawA[8], rawB[8];
            int tgA[4], tgB[4]; float scA[4], scB[4];
            loadT(s0, rawA, tgA, scA);                       // prologue
            for (int t0 = s0; t0 < s1; t0 += 32) {
                const int t1 = t0 + 16;
                if (t1 < s1) loadT(t1, rawB, tgB, scB);      // prefetch
                computeT(rawA, tgA, scA);
                if (t1 < s1) {
                    if (t1 + 16 < s1) loadT(t1 + 16, rawA, tgA, scA);
                    computeT(rawB, tgB, scB);
                }
            }
        }
        __syncthreads();
        // fused ReLU + f32 store into concat slot
        for (int q = tid; q < nIn * 32; q += 256) {
            int r = q >> 5, c = (q & 31) * 4;
            float4 v = *reinterpret_cast<const float4*>(&accS[r * 132 + c]);
            v.x = fmaxf(v.x, 0.f); v.y = fmaxf(v.y, 0.f);
            v.z = fmaxf(v.z, 0.f); v.w = fmaxf(v.w, 0.f);
            *reinterpret_cast<float4*>(out + (size_t)(node0 + r) * 512 + colOff + c) = v;
        }
        __syncthreads();   // accS reuse safety before next job's init
    }
}

__global__ void emb_copy(const float* __restrict__ emb, float* __restrict__ out) {
    int q = blockIdx.x * 256 + threadIdx.x;
    int n = q >> 5, c = (q & 31) * 4;
    float4 v = *reinterpret_cast<const float4*>(emb + (size_t)n * 128 + c);
    *reinterpret_cast<float4*>(out + (size_t)n * 512 + 384 + c) = v;
}

extern "C" void kernel_launch(void* const* d_in, const int* in_sizes, int n_in,
                              void* d_out, int out_size, void* d_ws, size_t ws_size,
                              hipStream_t stream) {
    const float* emb = (const float*)d_in[0];
    const float* comp[3]  = {(const float*)d_in[1], (const float*)d_in[5], (const float*)d_in[9]};
    const float* basis[3] = {(const float*)d_in[2], (const float*)d_in[6], (const float*)d_in[10]};
    const float* root[3]  = {(const float*)d_in[3], (const float*)d_in[7], (const float*)d_in[11]};
    const float* bias[3]  = {(const float*)d_in[4], (const float*)d_in[8], (const float*)d_in[12]};
    const int* src = (const int*)d_in[13];
    const int* tgt = (const int*)d_in[14];
    const int* et  = (const int*)d_in[15];
    float* out = (float*)d_out;

    char* ws = (char*)d_ws;
    float* invcnt = (float*)(ws + WS_INVCNT);
    int*   offs   = (int*)(ws + WS_OFFS);
    int*   cur    = (int*)(ws + WS_CUR);
    int2*  eMeta  = (int2*)(ws + WS_EMETA);
    u16*   Wthi   = (u16*)(ws + WS_WTHI);
    u16*   Wtlo   = (u16*)(ws + WS_WTLO);
    int*   jobCtr = (int*)(ws + WS_CTR);
    if (ws_size < (size_t)WS_END) return;

    hipMemsetAsync(invcnt, 0, 6400000, stream);
    hipMemsetAsync(cur, 0, NKEYS * 4, stream);
    hipMemsetAsync(jobCtr, 0, 16, stream);
    hist_kernel<<<6250, 256, 0, stream>>>(tgt, et, invcnt, cur);
    scan_kernel<<<1, 256, 0, stream>>>(cur, offs);
    invcnt_kernel<<<6250, 256, 0, stream>>>(invcnt);
    scatter_edges<<<6250, 256, 0, stream>>>(src, tgt, et, invcnt, cur, eMeta);

    // layer l: x from emb (stride 128) or the previous layer's out slot (stride 512)
    const float* xin[3] = {emb, out + 256, out + 128};
    const int    xs[3]  = {128, 512, 512};
    const int    colOff[3] = {256, 128, 0};

    for (int lyr = 0; lyr < 3; ++lyr) {
        wprep_kernel<<<272, 256, 0, stream>>>(comp[lyr], basis[lyr], root[lyr], Wthi, Wtlo);
        layer_mfma<<<GRID_MFMA, 256, 0, stream>>>(xin[lyr], xs[lyr], Wthi, Wtlo, bias[lyr],
                                                  eMeta, offs, jobCtr + lyr, out, colOff[lyr]);
    }
    emb_copy<<<12500, 256, 0, stream>>>(emb, out);
}